// Round 3
// baseline (317.748 us; speedup 1.0000x reference)
//
#include <hip/hip_runtime.h>

// ---- problem constants ----
constexpr int N    = 20000;
constexpr int T    = 12;
constexpr int C    = 256;
constexpr int HIDN = 128;
constexpr int OUTD = 12;
constexpr int ER   = 30000;
constexpr int NFT  = 48;               // F*T floats per node
constexpr int EDGE_TOT = 5 * ER;       // 150000
constexpr int CAP      = 32;           // combined bucket capacity (mean 7.5 edges/node)
constexpr int EB       = 586;          // edge blocks = ceil(150000/256)
constexpr int PREP_B   = 152 + EB;     // 738 prep role-blocks
constexpr int NT       = N / 16;       // 1250 node tiles
constexpr int GRID     = 1024;         // co-resident by construction (see k_all note)

// workspace layout (4-byte units); deg+cnt+Mv contiguous -> ONE zero phase
constexpr int WS_DEG    = 0;          // [100000] float
constexpr int WS_CNT    = 100000;     // [20000] int
constexpr int WS_MV     = 120000;     // [10*C + T] float (atomically accumulated)
constexpr int WS_ZEND   = 122576;     // zero end (floats)
constexpr int WS_WP     = 122576;     // 32768 bf16 = 16384 floats (W1 B-frags)
constexpr int WS_W2T    = 138960;     // [OUTD*HIDN] float
constexpr int WS_BUCKET = 140496;     // [N*CAP] int2 (src|r<<15, w-bits), 8B-aligned

constexpr float LOG2E = 1.4426950408889634f;

typedef __attribute__((ext_vector_type(8))) short short8;
typedef __attribute__((ext_vector_type(4))) float floatx4;
typedef __attribute__((ext_vector_type(2))) float floatx2;

#if __has_builtin(__builtin_amdgcn_exp2f)
#define EXP2(x) __builtin_amdgcn_exp2f(x)
#else
#define EXP2(x) exp2f(x)
#endif

__device__ __forceinline__ floatx2 pk_fma(floatx2 a, floatx2 b, floatx2 c) {
  floatx2 r;
  r.x = fmaf(a.x, b.x, c.x);
  r.y = fmaf(a.y, b.y, c.y);
  return r;                            // -> v_pk_fma_f32
}

__device__ __forceinline__ short f2bf(float f) {   // RNE float->bf16
  unsigned u = __float_as_uint(f);
  u = u + 0x7fffu + ((u >> 16) & 1u);
  return (short)(u >> 16);
}

__device__ __forceinline__ void pick_region(
    int r,
    const int* e0, const int* e1, const int* e2, const int* e3, const int* e4,
    const float* a0, const float* a1, const float* a2, const float* a3, const float* a4,
    const int*& ei, const float*& ea) {
  switch (r) {
    case 0: ei = e0; ea = a0; break;
    case 1: ei = e1; ea = a1; break;
    case 2: ei = e2; ea = a2; break;
    case 3: ei = e3; ea = a3; break;
    default: ei = e4; ea = a4; break;
  }
}

// Manual grid barrier: monotone epoch counter in device .bss (starts 0 at
// module load, NEVER reset -> stays a multiple of GRID forever, incl. across
// graph replays and rocprof counter-group replays; GRID is a power of two so
// u32 wrap preserves the invariant).  thread 0 arrives with an agent-scope
// ACQ_REL fetch_add (publishes this block's writes: L2 writeback) and spins
// on an ACQUIRE load (invalidates L1/L2 before post-barrier reads).  All
// other threads are ordered by __syncthreads (racy lines were never in their
// L1: pre-barrier writes are write-through stores / atomics, reads only
// happen post-barrier).
__device__ unsigned g_bar[2];

__device__ __forceinline__ void grid_barrier(int which) {
  __syncthreads();
  if (threadIdx.x == 0) {
    unsigned v = __hip_atomic_fetch_add(&g_bar[which], 1u,
                                        __ATOMIC_ACQ_REL, __HIP_MEMORY_SCOPE_AGENT);
    unsigned target = (v & ~(unsigned)(GRID - 1)) + (unsigned)GRID;
    while (__hip_atomic_load(&g_bar[which], __ATOMIC_ACQUIRE,
                             __HIP_MEMORY_SCOPE_AGENT) < target)
      __builtin_amdgcn_s_sleep(1);
  }
  __syncthreads();
}

// Single ordinary-launch kernel: phase Z (zero) -> grid barrier -> phase P
// (prep: Mv collapse / softmax / W1 repack / edge atomics + bucket fill) ->
// grid barrier -> phase F (gather + gates + attention pooling + MLP,
// grid-strided over 1250 tiles).
// Co-residency arithmetic (required for the manual barrier): LDS 19968B ->
// 8 blocks/CU; __launch_bounds__(256,4) caps VGPR at 128 -> >=4 blocks/CU;
// 4 x 256 CUs = 1024 = GRID blocks guaranteed simultaneously resident.
// NOTE: no `return` before the barriers — every thread reaches both.
__global__ __launch_bounds__(256, 4) void k_all(
    const float* __restrict__ Wc_z, const float* __restrict__ bc_z,
    const float* __restrict__ Wl_z, const float* __restrict__ bl_z,
    const float* __restrict__ Wc_h, const float* __restrict__ bc_h,
    const float* __restrict__ Wl_h, const float* __restrict__ bl_h,
    const float* __restrict__ att, const float* __restrict__ W1,
    const float* __restrict__ W2,
    const int* __restrict__ e0, const int* __restrict__ e1,
    const int* __restrict__ e2, const int* __restrict__ e3,
    const int* __restrict__ e4,
    const float* __restrict__ a0, const float* __restrict__ a1,
    const float* __restrict__ a2, const float* __restrict__ a3,
    const float* __restrict__ a4,
    const float* __restrict__ x, const float* __restrict__ b1,
    const float* __restrict__ b2,
    float* __restrict__ Mv, short* __restrict__ Wp, float* __restrict__ W2t,
    float* __restrict__ deg, int* __restrict__ cnt, int2* __restrict__ bucket,
    float* __restrict__ y_out, float* __restrict__ h_out) {
  __shared__ float xs[16][NFT];       // gathered features (rows 192B, 16B-aligned)
  __shared__ short hs[16][264];       // bf16 relu(h), pad 256->264
  __shared__ float y1s[16][132];      // fp32 layer-1 out, pad 128->132

  int b = blockIdx.x, tid = threadIdx.x;

  // ---- phase Z: zero deg + cnt + Mv (contiguous; deg is the ws base) ----
  {
    int gz = b * 256 + tid;
    if (gz < WS_ZEND) deg[gz] = 0.0f;
  }
  grid_barrier(0);

  // ---- phase P: prep (block-role split; no early returns) ----
  if (b < 16) {
    int g  = b >> 3;
    int ch = b & 7;
    int k  = tid;
    const float* Wc = g ? Wc_h : Wc_z;
    const float* bc = g ? bc_h : bc_z;
    const float* Wl = g ? Wl_h : Wl_z;
    const float* bl = g ? bl_h : bl_z;
    float scale = g ? 2.0f * LOG2E : LOG2E;
    float m0 = 0.f, m1 = 0.f, m2 = 0.f, m3 = 0.f;
    float v = (ch == 0) ? bl[k] : 0.0f;
    int c0 = ch * 32;
    for (int c = c0; c < c0 + 32; c++) {
      float wl = Wl[c * C + k];
      m0 = fmaf(Wc[0 * C + c], wl, m0);
      m1 = fmaf(Wc[1 * C + c], wl, m1);
      m2 = fmaf(Wc[2 * C + c], wl, m2);
      m3 = fmaf(Wc[3 * C + c], wl, m3);
      v  = fmaf(bc[c], wl, v);
    }
    float* o = Mv + g * (5 * C);
    atomicAdd(&o[0 * C + k], scale * m0);
    atomicAdd(&o[1 * C + k], scale * m1);
    atomicAdd(&o[2 * C + k], scale * m2);
    atomicAdd(&o[3 * C + k], scale * m3);
    atomicAdd(&o[4 * C + k], scale * v);
  } else if (b == 16) {
    if (tid < T) {
      float amax = -3.0e38f;
      for (int t = 0; t < T; t++) amax = fmaxf(amax, att[t]);
      float s = 0.f;
      for (int t = 0; t < T; t++) s += __expf(att[t] - amax);
      Mv[10 * C + tid] = __expf(att[tid] - amax) / s;
    }
  } else if (b < 152) {
    int idx = (b - 17) * 256 + tid;
    if (idx < 32768) {
      int j    = idx & 7;
      int lane = (idx >> 3) & 63;
      int ch   = (idx >> 9) & 7;
      int kt   = idx >> 12;
      int cin  = ch * 32 + (lane >> 4) * 8 + j;   // K index
      int kout = kt * 16 + (lane & 15);           // N index
      Wp[idx] = f2bf(W1[cin * HIDN + kout]);
    } else if (idx < 32768 + 1536) {
      int r = idx - 32768;
      int o = r >> 7, k = r & 127;
      W2t[r] = W2[k * OUTD + o];
    }
  } else if (b < PREP_B) {
    int i = (b - 152) * 256 + tid;
    if (i < EDGE_TOT) {
      int r = i / ER;
      int e = i - r * ER;
      const int* ei; const float* ea;
      pick_region(r, e0, e1, e2, e3, e4, a0, a1, a2, a3, a4, ei, ea);
      int src = ei[e];
      int dst = ei[ER + e];
      float w = ea[e];
      atomicAdd(&deg[r * N + dst], w);
      int slot = atomicAdd(&cnt[dst], 1);
      if (slot < CAP) bucket[dst * CAP + slot] = make_int2(src | (r << 15), __float_as_int(w));
    }
  }
  grid_barrier(1);

  // ---- phase F: fused gather + gates + pooling + MLP (grid-stride tiles) ----
  int wave = tid >> 6, lane = tid & 63;

  for (int tile = b; tile < NT; tile += GRID) {
    int n0 = tile * 16;

    // gather: 4 nodes per wave, lane = feature q.  All 4 nodes' edge loops
    // run in ONE unified loop to max(cvr) (trip counts in SGPRs via
    // readfirstlane -> scalar branches); masked slots carry cf=0/src=0 so
    // short nodes are no-ops.  Up to 16 independent x-row loads in flight.
    {
      int q = lane < NFT ? lane : NFT - 1;
      int sl = lane & (CAP - 1);
      int nb = n0 + wave * 4;
      int4 cv4 = *(const int4*)&cnt[nb];
      int cvs[4];
      cvs[0] = __builtin_amdgcn_readfirstlane(cv4.x);
      cvs[1] = __builtin_amdgcn_readfirstlane(cv4.y);
      cvs[2] = __builtin_amdgcn_readfirstlane(cv4.z);
      cvs[3] = __builtin_amdgcn_readfirstlane(cv4.w);
#pragma unroll
      for (int nl = 0; nl < 4; nl++) cvs[nl] = cvs[nl] > CAP ? CAP : cvs[nl];

      int2 mrs[4];
#pragma unroll
      for (int nl = 0; nl < 4; nl++) mrs[nl] = bucket[(nb + nl) * CAP + sl];

      int srcs[4]; float cfs[4];
      float fa[4], fb[4], fc[4], fd[4];
#pragma unroll
      for (int nl = 0; nl < 4; nl++) {
        int n = nb + nl;
        float dd0 = rsqrtf(deg[0 * N + n] + 1.0f);
        float dd1 = rsqrtf(deg[1 * N + n] + 1.0f);
        float dd2 = rsqrtf(deg[2 * N + n] + 1.0f);
        float dd3 = rsqrtf(deg[3 * N + n] + 1.0f);
        float dd4 = rsqrtf(deg[4 * N + n] + 1.0f);
        float s = dd0 * dd0 + dd1 * dd1 + dd2 * dd2 + dd3 * dd3 + dd4 * dd4;
        fa[nl] = s * x[n * NFT + q];
        fb[nl] = 0.f; fc[nl] = 0.f; fd[nl] = 0.f;

        bool valid = sl < cvs[nl];
        int key  = valid ? mrs[nl].x : 0;       // masked -> node 0, cf 0
        int srcv = key & 0x7fff;
        int rr   = key >> 15;
        float dsrc = deg[rr * N + srcv];        // 32-lane random load (L2-resident)
        float ddn = rr == 0 ? dd0 : rr == 1 ? dd1 : rr == 2 ? dd2
                  : rr == 3 ? dd3 : dd4;
        cfs[nl]  = valid ? rsqrtf(dsrc + 1.0f) * __int_as_float(mrs[nl].y) * ddn : 0.0f;
        srcs[nl] = srcv;
      }

      int cvr0 = (cvs[0] + 3) & ~3, cvr1 = (cvs[1] + 3) & ~3;
      int cvr2 = (cvs[2] + 3) & ~3, cvr3 = (cvs[3] + 3) & ~3;
      int cvm01 = cvr0 > cvr1 ? cvr0 : cvr1;
      int cvm23 = cvr2 > cvr3 ? cvr2 : cvr3;
      int cvm = cvm01 > cvm23 ? cvm01 : cvm23;
      int cvr[4] = {cvr0, cvr1, cvr2, cvr3};

      for (int j = 0; j < cvm; j += 4) {
#pragma unroll
        for (int nl = 0; nl < 4; nl++) {
          if (j < cvr[nl]) {                    // SGPR condition -> s_cbranch
            int s0 = __shfl(srcs[nl], j);
            int s1 = __shfl(srcs[nl], j + 1);
            int s2 = __shfl(srcs[nl], j + 2);
            int s3 = __shfl(srcs[nl], j + 3);
            float c0 = __shfl(cfs[nl], j);
            float c1 = __shfl(cfs[nl], j + 1);
            float c2 = __shfl(cfs[nl], j + 2);
            float c3 = __shfl(cfs[nl], j + 3);
            float x0 = x[s0 * NFT + q];
            float x1 = x[s1 * NFT + q];
            float x2 = x[s2 * NFT + q];
            float x3 = x[s3 * NFT + q];
            fa[nl] = fmaf(c0, x0, fa[nl]);
            fb[nl] = fmaf(c1, x1, fb[nl]);
            fc[nl] = fmaf(c2, x2, fc[nl]);
            fd[nl] = fmaf(c3, x3, fd[nl]);
          }
        }
      }
#pragma unroll
      for (int nl = 0; nl < 4; nl++) {
        float facc = (fa[nl] + fb[nl]) + (fc[nl] + fd[nl]);
        if (lane < NFT) xs[wave * 4 + nl][lane] = facc;
      }
    }
    __syncthreads();

    // gates: half = wave&1, nodes (wave>>1)*8..+8, 2 ch/lane
    {
      int half = wave & 1;
      int nb   = (wave >> 1) * 8;
      int c0 = half * 128 + (lane << 1);
      const float* Mz = Mv;               // pre-scaled by log2e
      const float* Mh = Mv + 5 * C;       // pre-scaled by 2*log2e
      floatx2 mz[4], mh[4], vz, vh;
#pragma unroll
      for (int f = 0; f < 4; f++) {
        mz[f] = *(const floatx2*)(Mz + f * C + c0);
        mh[f] = *(const floatx2*)(Mh + f * C + c0);
      }
      vz = *(const floatx2*)(Mz + 4 * C + c0);
      vh = *(const floatx2*)(Mh + 4 * C + c0);

#pragma unroll
      for (int nl = 0; nl < 8; nl++) {
        int rl = nb + nl;                  // local node 0..15
        int n = n0 + rl;
        const float* xr = &xs[rl][0];      // LDS, broadcast reads
        floatx2 acc = {0.f, 0.f};
#pragma unroll
        for (int tb = 0; tb < 3; tb++) {
          float4 xf0 = *(const float4*)(xr + 0 * T + tb * 4);
          float4 xf1 = *(const float4*)(xr + 1 * T + tb * 4);
          float4 xf2 = *(const float4*)(xr + 2 * T + tb * 4);
          float4 xf3 = *(const float4*)(xr + 3 * T + tb * 4);
          float xs0[4] = {xf0.x, xf0.y, xf0.z, xf0.w};
          float xs1[4] = {xf1.x, xf1.y, xf1.z, xf1.w};
          float xs2[4] = {xf2.x, xf2.y, xf2.z, xf2.w};
          float xs3[4] = {xf3.x, xf3.y, xf3.z, xf3.w};
#pragma unroll
          for (int tt = 0; tt < 4; tt++) {
            int t = tb * 4 + tt;
            float p = Mv[10 * C + t];      // uniform address -> s_load
            floatx2 x0 = {xs0[tt], xs0[tt]};
            floatx2 x1 = {xs1[tt], xs1[tt]};
            floatx2 x2 = {xs2[tt], xs2[tt]};
            floatx2 x3 = {xs3[tt], xs3[tt]};
            floatx2 az = pk_fma(mz[0], x0, pk_fma(mz[1], x1, pk_fma(mz[2], x2, pk_fma(mz[3], x3, vz))));
            floatx2 ah = pk_fma(mh[0], x0, pk_fma(mh[1], x1, pk_fma(mh[2], x2, pk_fma(mh[3], x3, vh))));
            floatx2 e1, e2;
            e1.x = EXP2(az.x); e1.y = EXP2(az.y);        // e^{az_true}
            e2.x = EXP2(ah.x); e2.y = EXP2(ah.y);        // e^{2*ah_true}
            floatx2 one = {1.f, 1.f};
            floatx2 d1 = e1 + one;
            floatx2 d2 = e2 + one;
            floatx2 rD;
            rD.x = __builtin_amdgcn_rcpf(d1.x * d2.x);
            rD.y = __builtin_amdgcn_rcpf(d1.y * d2.y);
            floatx2 pv = {p, p};
            floatx2 pn = pk_fma(pv, e2, -pv);            // p*(e2-1)
            acc = pk_fma(pn, rD, acc);
          }
        }
        float2 o = {acc.x, acc.y};
        *(float2*)(h_out + n * C + c0) = o;               // required fp32 output
        unsigned pk = (unsigned short)f2bf(fmaxf(acc.x, 0.f)) |
                      ((unsigned)(unsigned short)f2bf(fmaxf(acc.y, 0.f)) << 16);
        *(unsigned*)&hs[rl][c0] = pk;                     // bf16 relu(h) -> LDS
      }
    }
    __syncthreads();

    // layer 1: 16 MFMAs per wave (kt = wave*2, wave*2+1)
    {
      int quad = lane >> 4, col = lane & 15;
      floatx4 acc2[2];
      acc2[0] = {0.f, 0.f, 0.f, 0.f};
      acc2[1] = {0.f, 0.f, 0.f, 0.f};
#pragma unroll
      for (int ch = 0; ch < 8; ch++) {
        short8 a = *(const short8*)&hs[col][ch * 32 + quad * 8];
#pragma unroll
        for (int kk = 0; kk < 2; kk++) {
          short8 bb = ((const short8*)Wp)[((wave * 2 + kk) * 8 + ch) * 64 + lane];
          acc2[kk] = __builtin_amdgcn_mfma_f32_16x16x32_bf16(a, bb, acc2[kk], 0, 0, 0);
        }
      }
#pragma unroll
      for (int kk = 0; kk < 2; kk++) {
        int kt = wave * 2 + kk;
        float bias = b1[kt * 16 + col];
#pragma unroll
        for (int r = 0; r < 4; r++)
          y1s[quad * 4 + r][kt * 16 + col] = fmaxf(acc2[kk][r] + bias, 0.f);
      }
    }
    __syncthreads();

    // layer 2: 16 nodes x 12 outputs = 192 threads
    if (tid < 16 * OUTD) {
      int nl = tid / OUTD, o = tid - nl * OUTD;
      float sacc = b2[o];
      const float* yr = &y1s[nl][0];
      const float* wr = W2t + o * HIDN;
#pragma unroll 8
      for (int k4 = 0; k4 < 32; k4++) {
        float4 yv = *(const float4*)(yr + 4 * k4);
        float4 wv = *(const float4*)(wr + 4 * k4);
        sacc = fmaf(yv.x, wv.x, fmaf(yv.y, wv.y, fmaf(yv.z, wv.z, fmaf(yv.w, wv.w, sacc))));
      }
      y_out[(n0 + nl) * OUTD + o] = sacc;
    }
    __syncthreads();   // protect y1s/hs before next tile's phases
  }
}

extern "C" void kernel_launch(void* const* d_in, const int* in_sizes, int n_in,
                              void* d_out, int out_size, void* d_ws, size_t ws_size,
                              hipStream_t stream) {
  const float* x   = (const float*)d_in[0];
  // d_in[1] full-graph edge_index: provably unused
  const int* eIA = (const int*)d_in[2];
  const int* eKS = (const int*)d_in[3];
  const int* eKY = (const int*)d_in[4];
  const int* eOH = (const int*)d_in[5];
  const int* eWI = (const int*)d_in[6];
  const float* aIA = (const float*)d_in[7];
  const float* aKS = (const float*)d_in[8];
  const float* aKY = (const float*)d_in[9];
  const float* aOH = (const float*)d_in[10];
  const float* aWI = (const float*)d_in[11];
  const float* Wc_z = (const float*)d_in[12];
  const float* bc_z = (const float*)d_in[13];
  const float* Wl_z = (const float*)d_in[14];
  const float* bl_z = (const float*)d_in[15];
  // r-gate params (16..19) cannot influence the output (H=0)
  const float* Wc_h = (const float*)d_in[20];
  const float* bc_h = (const float*)d_in[21];
  const float* Wl_h = (const float*)d_in[22];
  const float* bl_h = (const float*)d_in[23];
  const float* att  = (const float*)d_in[24];
  const float* W1   = (const float*)d_in[25];
  const float* b1   = (const float*)d_in[26];
  const float* W2   = (const float*)d_in[27];
  const float* b2   = (const float*)d_in[28];

  float* ws     = (float*)d_ws;
  float* deg    = ws + WS_DEG;
  int*   cnt    = (int*)(ws + WS_CNT);
  float* Mv     = ws + WS_MV;
  short* Wp     = (short*)(ws + WS_WP);
  float* W2t    = ws + WS_W2T;
  int2*  bucket = (int2*)(ws + WS_BUCKET);

  float* y_out = (float*)d_out;            // [N,12]
  float* h_out = y_out + N * OUTD;         // [N,256]

  k_all<<<GRID, 256, 0, stream>>>(Wc_z, bc_z, Wl_z, bl_z,
                                  Wc_h, bc_h, Wl_h, bl_h,
                                  att, W1, W2,
                                  eIA, eKS, eKY, eOH, eWI,
                                  aIA, aKS, aKY, aOH, aWI,
                                  x, b1, b2,
                                  Mv, Wp, W2t,
                                  deg, cnt, bucket,
                                  y_out, h_out);
}

// Round 4
// 226.178 us; speedup vs baseline: 1.4049x; 1.4049x over previous
//
#include <hip/hip_runtime.h>

// ---- problem constants ----
constexpr int N    = 20000;
constexpr int T    = 12;
constexpr int C    = 256;
constexpr int HIDN = 128;
constexpr int OUTD = 12;
constexpr int ER   = 30000;
constexpr int NFT  = 48;               // F*T floats per node
constexpr int EDGE_TOT = 5 * ER;       // 150000
constexpr int CAP      = 32;           // combined bucket capacity (mean 7.5 edges/node)
constexpr int EB       = 586;          // edge blocks = ceil(150000/256)
constexpr int NT       = N / 16;       // 1250 node tiles
constexpr int FGRID    = 2048;         // 8 blocks/CU exactly (persistent, work-stealing)

// workspace layout (4-byte units); deg+cnt+Mv+tctr contiguous -> ONE memset
constexpr int WS_DEG    = 0;          // [100000] float
constexpr int WS_CNT    = 100000;     // [20000] int
constexpr int WS_MV     = 120000;     // [10*C + T] float (atomically accumulated)
constexpr int WS_TCTR   = 122572;     // [1] int tile counter (inside memset range)
constexpr int WS_ZEND   = 122576;     // memset end (floats)
constexpr int WS_WP     = 122576;     // 32768 bf16 = 16384 floats (W1 B-frags)
constexpr int WS_W2T    = 138960;     // [OUTD*HIDN] float
constexpr int WS_BUCKET = 140496;     // [N*CAP] int2 (src|r<<15, w-bits), 8B-aligned

constexpr float LOG2E = 1.4426950408889634f;

typedef __attribute__((ext_vector_type(8))) short short8;
typedef __attribute__((ext_vector_type(4))) float floatx4;
typedef __attribute__((ext_vector_type(2))) float floatx2;

#if __has_builtin(__builtin_amdgcn_exp2f)
#define EXP2(x) __builtin_amdgcn_exp2f(x)
#else
#define EXP2(x) exp2f(x)
#endif

__device__ __forceinline__ floatx2 pk_fma(floatx2 a, floatx2 b, floatx2 c) {
  floatx2 r;
  r.x = fmaf(a.x, b.x, c.x);
  r.y = fmaf(a.y, b.y, c.y);
  return r;                            // -> v_pk_fma_f32
}

__device__ __forceinline__ short f2bf(float f) {   // RNE float->bf16
  unsigned u = __float_as_uint(f);
  u = u + 0x7fffu + ((u >> 16) & 1u);
  return (short)(u >> 16);
}

__device__ __forceinline__ void pick_region(
    int r,
    const int* e0, const int* e1, const int* e2, const int* e3, const int* e4,
    const float* a0, const float* a1, const float* a2, const float* a3, const float* a4,
    const int*& ei, const float*& ea) {
  switch (r) {
    case 0: ei = e0; ea = a0; break;
    case 1: ei = e1; ea = a1; break;
    case 2: ei = e2; ea = a2; break;
    case 3: ei = e3; ea = a3; break;
    default: ei = e4; ea = a4; break;
  }
}

// 1) single prep pass (order-independent; coef math deferred to k_fused):
//    b<64      : weight-collapse PARTIALS, 8 c's per block with UNROLLED loop
//                (kills the 32-iter serial load-latency chain of the old 16-block
//                split) -> atomicAdd Mv (z pre-scaled log2e, h 2*log2e)
//    b==64     : softmax(att)
//    65<=b<200 : W1 -> bf16 MFMA-B frags; W2 -> W2t
//    b>=200    : deg[r*N+dst] += w  AND  bucket[dst] push (src|r<<15, raw w)
__global__ void k_prep(
    const float* __restrict__ Wc_z, const float* __restrict__ bc_z,
    const float* __restrict__ Wl_z, const float* __restrict__ bl_z,
    const float* __restrict__ Wc_h, const float* __restrict__ bc_h,
    const float* __restrict__ Wl_h, const float* __restrict__ bl_h,
    const float* __restrict__ att, const float* __restrict__ W1,
    const float* __restrict__ W2,
    const int* __restrict__ e0, const int* __restrict__ e1,
    const int* __restrict__ e2, const int* __restrict__ e3,
    const int* __restrict__ e4,
    const float* __restrict__ a0, const float* __restrict__ a1,
    const float* __restrict__ a2, const float* __restrict__ a3,
    const float* __restrict__ a4,
    float* __restrict__ Mv, short* __restrict__ Wp, float* __restrict__ W2t,
    float* __restrict__ deg, int* __restrict__ cnt, int2* __restrict__ bucket) {
  int b = blockIdx.x, tid = threadIdx.x;
  if (b < 64) {
    int g  = b >> 5;                  // 0: z-gate, 1: h-gate
    int ch = b & 31;                  // 32 chunks of 8 c's
    int k  = tid;
    const float* Wc = g ? Wc_h : Wc_z;
    const float* bc = g ? bc_h : bc_z;
    const float* Wl = g ? Wl_h : Wl_z;
    const float* bl = g ? bl_h : bl_z;
    float scale = g ? 2.0f * LOG2E : LOG2E;
    float m0 = 0.f, m1 = 0.f, m2 = 0.f, m3 = 0.f;
    float v = (ch == 0) ? bl[k] : 0.0f;
    int c0 = ch * 8;
#pragma unroll
    for (int cc = 0; cc < 8; cc++) {
      int c = c0 + cc;
      float wl = Wl[c * C + k];
      m0 = fmaf(Wc[0 * C + c], wl, m0);
      m1 = fmaf(Wc[1 * C + c], wl, m1);
      m2 = fmaf(Wc[2 * C + c], wl, m2);
      m3 = fmaf(Wc[3 * C + c], wl, m3);
      v  = fmaf(bc[c], wl, v);
    }
    float* o = Mv + g * (5 * C);
    atomicAdd(&o[0 * C + k], scale * m0);
    atomicAdd(&o[1 * C + k], scale * m1);
    atomicAdd(&o[2 * C + k], scale * m2);
    atomicAdd(&o[3 * C + k], scale * m3);
    atomicAdd(&o[4 * C + k], scale * v);
    return;
  }
  if (b == 64) {
    if (tid < T) {
      float amax = -3.0e38f;
      for (int t = 0; t < T; t++) amax = fmaxf(amax, att[t]);
      float s = 0.f;
      for (int t = 0; t < T; t++) s += __expf(att[t] - amax);
      Mv[10 * C + tid] = __expf(att[tid] - amax) / s;
    }
    return;
  }
  if (b < 200) {
    int idx = (b - 65) * 256 + tid;
    if (idx < 32768) {
      int j    = idx & 7;
      int lane = (idx >> 3) & 63;
      int ch   = (idx >> 9) & 7;
      int kt   = idx >> 12;
      int cin  = ch * 32 + (lane >> 4) * 8 + j;   // K index
      int kout = kt * 16 + (lane & 15);           // N index
      Wp[idx] = f2bf(W1[cin * HIDN + kout]);
    } else if (idx < 32768 + 1536) {
      int r = idx - 32768;
      int o = r >> 7, k = r & 127;
      W2t[r] = W2[k * OUTD + o];
    }
    return;
  }
  int i = (b - 200) * 256 + tid;
  if (i >= EDGE_TOT) return;
  int r = i / ER;
  int e = i - r * ER;
  const int* ei; const float* ea;
  pick_region(r, e0, e1, e2, e3, e4, a0, a1, a2, a3, a4, ei, ea);
  int src = ei[e];
  int dst = ei[ER + e];
  float w = ea[e];
  atomicAdd(&deg[r * N + dst], w);
  int slot = atomicAdd(&cnt[dst], 1);
  if (slot < CAP) bucket[dst * CAP + slot] = make_int2(src | (r << 15), __float_as_int(w));
}

// 2) fused gather + gates + attention pooling + MLP.  PERSISTENT blocks:
//    grid = 2048 (8 blocks/CU exactly; LDS 8x19968 = 156KB <= 160KB), each
//    block pops 16-node tiles from an atomic counter -> perfect per-CU load
//    balance (1250 tiles / 4.88 per CU used to leave a 5-vs-4 block tail).
//    Gather: 4 nodes/wave, lane = feature q; bucket slots in lanes 0..31,
//    per-slot coef computed wave-parallel (deferred-coef), then the 4 nodes'
//    edge loops run UNIFIED to max(cvr) with SGPR trip counts -> up to 16
//    independent x-row loads in flight.  Gates: wave owns half (w&1) of all
//    16 nodes, lane owns 2 channels; p[t] hoisted per-wave.  fp32 h ->
//    global, bf16 relu(h) -> LDS.  16 MFMAs/wave layer-1 + tiny layer-2.
__global__ __launch_bounds__(256) void k_fused(
    const float* __restrict__ x, const float* __restrict__ deg,
    const int* __restrict__ cnt, const int2* __restrict__ bucket,
    const float* __restrict__ Mv, const short* __restrict__ Wp,
    const float* __restrict__ b1, const float* __restrict__ W2t,
    const float* __restrict__ b2, int* __restrict__ tctr,
    float* __restrict__ y_out, float* __restrict__ h_out) {
  __shared__ float xs[16][NFT];       // gathered features (rows 192B, 16B-aligned)
  __shared__ short hs[16][264];       // bf16 relu(h), pad 256->264
  __shared__ float y1s[16][132];      // fp32 layer-1 out, pad 128->132
  __shared__ int stile;
  int tid = threadIdx.x;
  int wave = tid >> 6, lane = tid & 63;

  for (;;) {
    if (tid == 0) stile = atomicAdd(tctr, 1);
    __syncthreads();
    int tile = stile;
    if (tile >= NT) break;
    int n0 = tile * 16;

    // ---- gather phase ----
    {
      int q = lane < NFT ? lane : NFT - 1;
      int sl = lane & (CAP - 1);
      int nb = n0 + wave * 4;
      int4 cv4 = *(const int4*)&cnt[nb];
      int cvs[4];
      cvs[0] = __builtin_amdgcn_readfirstlane(cv4.x);
      cvs[1] = __builtin_amdgcn_readfirstlane(cv4.y);
      cvs[2] = __builtin_amdgcn_readfirstlane(cv4.z);
      cvs[3] = __builtin_amdgcn_readfirstlane(cv4.w);
#pragma unroll
      for (int nl = 0; nl < 4; nl++) cvs[nl] = cvs[nl] > CAP ? CAP : cvs[nl];

      int2 mrs[4];
#pragma unroll
      for (int nl = 0; nl < 4; nl++) mrs[nl] = bucket[(nb + nl) * CAP + sl];

      int srcs[4]; float cfs[4];
      float fa[4], fb[4], fc[4], fd[4];
#pragma unroll
      for (int nl = 0; nl < 4; nl++) {
        int n = nb + nl;
        float dd0 = rsqrtf(deg[0 * N + n] + 1.0f);
        float dd1 = rsqrtf(deg[1 * N + n] + 1.0f);
        float dd2 = rsqrtf(deg[2 * N + n] + 1.0f);
        float dd3 = rsqrtf(deg[3 * N + n] + 1.0f);
        float dd4 = rsqrtf(deg[4 * N + n] + 1.0f);
        float s = dd0 * dd0 + dd1 * dd1 + dd2 * dd2 + dd3 * dd3 + dd4 * dd4;
        fa[nl] = s * x[n * NFT + q];
        fb[nl] = 0.f; fc[nl] = 0.f; fd[nl] = 0.f;

        bool valid = sl < cvs[nl];
        int key  = valid ? mrs[nl].x : 0;       // masked -> node 0, cf 0
        int srcv = key & 0x7fff;
        int rr   = key >> 15;
        float dsrc = deg[rr * N + srcv];        // 32-lane random load (L2-resident)
        float ddn = rr == 0 ? dd0 : rr == 1 ? dd1 : rr == 2 ? dd2
                  : rr == 3 ? dd3 : dd4;
        cfs[nl]  = valid ? rsqrtf(dsrc + 1.0f) * __int_as_float(mrs[nl].y) * ddn : 0.0f;
        srcs[nl] = srcv;
      }

      int cvr0 = (cvs[0] + 3) & ~3, cvr1 = (cvs[1] + 3) & ~3;
      int cvr2 = (cvs[2] + 3) & ~3, cvr3 = (cvs[3] + 3) & ~3;
      int cvm01 = cvr0 > cvr1 ? cvr0 : cvr1;
      int cvm23 = cvr2 > cvr3 ? cvr2 : cvr3;
      int cvm = cvm01 > cvm23 ? cvm01 : cvm23;
      int cvr[4] = {cvr0, cvr1, cvr2, cvr3};

      for (int j = 0; j < cvm; j += 4) {
#pragma unroll
        for (int nl = 0; nl < 4; nl++) {
          if (j < cvr[nl]) {                    // SGPR condition -> s_cbranch
            int s0 = __shfl(srcs[nl], j);
            int s1 = __shfl(srcs[nl], j + 1);
            int s2 = __shfl(srcs[nl], j + 2);
            int s3 = __shfl(srcs[nl], j + 3);
            float c0 = __shfl(cfs[nl], j);
            float c1 = __shfl(cfs[nl], j + 1);
            float c2 = __shfl(cfs[nl], j + 2);
            float c3 = __shfl(cfs[nl], j + 3);
            float x0 = x[s0 * NFT + q];
            float x1 = x[s1 * NFT + q];
            float x2 = x[s2 * NFT + q];
            float x3 = x[s3 * NFT + q];
            fa[nl] = fmaf(c0, x0, fa[nl]);
            fb[nl] = fmaf(c1, x1, fb[nl]);
            fc[nl] = fmaf(c2, x2, fc[nl]);
            fd[nl] = fmaf(c3, x3, fd[nl]);
          }
        }
      }
#pragma unroll
      for (int nl = 0; nl < 4; nl++) {
        float facc = (fa[nl] + fb[nl]) + (fc[nl] + fd[nl]);
        if (lane < NFT) xs[wave * 4 + nl][lane] = facc;
      }
    }
    __syncthreads();

    // ---- gates phase: half = wave&1, nodes (wave>>1)*8..+8, 2 ch/lane ----
    {
      int half = wave & 1;
      int nb   = (wave >> 1) * 8;
      int c0 = half * 128 + (lane << 1);
      const float* Mz = Mv;               // pre-scaled by log2e
      const float* Mh = Mv + 5 * C;       // pre-scaled by 2*log2e
      floatx2 mz[4], mh[4], vz, vh;
#pragma unroll
      for (int f = 0; f < 4; f++) {
        mz[f] = *(const floatx2*)(Mz + f * C + c0);
        mh[f] = *(const floatx2*)(Mh + f * C + c0);
      }
      vz = *(const floatx2*)(Mz + 4 * C + c0);
      vh = *(const floatx2*)(Mh + 4 * C + c0);
      float pr[T];
#pragma unroll
      for (int t = 0; t < T; t++) pr[t] = Mv[10 * C + t];   // uniform -> s_load

#pragma unroll
      for (int nl = 0; nl < 8; nl++) {
        int rl = nb + nl;                  // local node 0..15
        int n = n0 + rl;
        const float* xr = &xs[rl][0];      // LDS, broadcast reads
        floatx2 acc = {0.f, 0.f};
#pragma unroll
        for (int tb = 0; tb < 3; tb++) {
          float4 xf0 = *(const float4*)(xr + 0 * T + tb * 4);
          float4 xf1 = *(const float4*)(xr + 1 * T + tb * 4);
          float4 xf2 = *(const float4*)(xr + 2 * T + tb * 4);
          float4 xf3 = *(const float4*)(xr + 3 * T + tb * 4);
          float xs0[4] = {xf0.x, xf0.y, xf0.z, xf0.w};
          float xs1[4] = {xf1.x, xf1.y, xf1.z, xf1.w};
          float xs2[4] = {xf2.x, xf2.y, xf2.z, xf2.w};
          float xs3[4] = {xf3.x, xf3.y, xf3.z, xf3.w};
#pragma unroll
          for (int tt = 0; tt < 4; tt++) {
            int t = tb * 4 + tt;
            float p = pr[t];
            floatx2 x0 = {xs0[tt], xs0[tt]};
            floatx2 x1 = {xs1[tt], xs1[tt]};
            floatx2 x2 = {xs2[tt], xs2[tt]};
            floatx2 x3 = {xs3[tt], xs3[tt]};
            floatx2 az = pk_fma(mz[0], x0, pk_fma(mz[1], x1, pk_fma(mz[2], x2, pk_fma(mz[3], x3, vz))));
            floatx2 ah = pk_fma(mh[0], x0, pk_fma(mh[1], x1, pk_fma(mh[2], x2, pk_fma(mh[3], x3, vh))));
            floatx2 e1, e2;
            e1.x = EXP2(az.x); e1.y = EXP2(az.y);        // e^{az_true}
            e2.x = EXP2(ah.x); e2.y = EXP2(ah.y);        // e^{2*ah_true}
            floatx2 one = {1.f, 1.f};
            floatx2 d1 = e1 + one;
            floatx2 d2 = e2 + one;
            floatx2 rD;
            rD.x = __builtin_amdgcn_rcpf(d1.x * d2.x);
            rD.y = __builtin_amdgcn_rcpf(d1.y * d2.y);
            floatx2 pv = {p, p};
            floatx2 pn = pk_fma(pv, e2, -pv);            // p*(e2-1)
            acc = pk_fma(pn, rD, acc);
          }
        }
        float2 o = {acc.x, acc.y};
        *(float2*)(h_out + n * C + c0) = o;               // required fp32 output
        unsigned pk = (unsigned short)f2bf(fmaxf(acc.x, 0.f)) |
                      ((unsigned)(unsigned short)f2bf(fmaxf(acc.y, 0.f)) << 16);
        *(unsigned*)&hs[rl][c0] = pk;                     // bf16 relu(h) -> LDS
      }
    }
    __syncthreads();

    // ---- layer 1: 16 MFMAs per wave (kt = wave*2, wave*2+1) ----
    {
      int quad = lane >> 4, col = lane & 15;
      floatx4 acc2[2];
      acc2[0] = {0.f, 0.f, 0.f, 0.f};
      acc2[1] = {0.f, 0.f, 0.f, 0.f};
#pragma unroll
      for (int ch = 0; ch < 8; ch++) {
        short8 a = *(const short8*)&hs[col][ch * 32 + quad * 8];
#pragma unroll
        for (int kk = 0; kk < 2; kk++) {
          short8 bb = ((const short8*)Wp)[((wave * 2 + kk) * 8 + ch) * 64 + lane];
          acc2[kk] = __builtin_amdgcn_mfma_f32_16x16x32_bf16(a, bb, acc2[kk], 0, 0, 0);
        }
      }
#pragma unroll
      for (int kk = 0; kk < 2; kk++) {
        int kt = wave * 2 + kk;
        float bias = b1[kt * 16 + col];
#pragma unroll
        for (int r = 0; r < 4; r++)
          y1s[quad * 4 + r][kt * 16 + col] = fmaxf(acc2[kk][r] + bias, 0.f);
      }
    }
    __syncthreads();

    // ---- layer 2: 16 nodes x 12 outputs = 192 threads ----
    if (tid < 16 * OUTD) {
      int nl = tid / OUTD, o = tid - nl * OUTD;
      float sacc = b2[o];
      const float* yr = &y1s[nl][0];
      const float* wr = W2t + o * HIDN;
#pragma unroll 8
      for (int k4 = 0; k4 < 32; k4++) {
        float4 yv = *(const float4*)(yr + 4 * k4);
        float4 wv = *(const float4*)(wr + 4 * k4);
        sacc = fmaf(yv.x, wv.x, fmaf(yv.y, wv.y, fmaf(yv.z, wv.z, fmaf(yv.w, wv.w, sacc))));
      }
      y_out[(n0 + nl) * OUTD + o] = sacc;
    }
    __syncthreads();   // protect y1s/hs/stile before next tile
  }
}

extern "C" void kernel_launch(void* const* d_in, const int* in_sizes, int n_in,
                              void* d_out, int out_size, void* d_ws, size_t ws_size,
                              hipStream_t stream) {
  const float* x   = (const float*)d_in[0];
  // d_in[1] full-graph edge_index: provably unused
  const int* eIA = (const int*)d_in[2];
  const int* eKS = (const int*)d_in[3];
  const int* eKY = (const int*)d_in[4];
  const int* eOH = (const int*)d_in[5];
  const int* eWI = (const int*)d_in[6];
  const float* aIA = (const float*)d_in[7];
  const float* aKS = (const float*)d_in[8];
  const float* aKY = (const float*)d_in[9];
  const float* aOH = (const float*)d_in[10];
  const float* aWI = (const float*)d_in[11];
  const float* Wc_z = (const float*)d_in[12];
  const float* bc_z = (const float*)d_in[13];
  const float* Wl_z = (const float*)d_in[14];
  const float* bl_z = (const float*)d_in[15];
  // r-gate params (16..19) cannot influence the output (H=0)
  const float* Wc_h = (const float*)d_in[20];
  const float* bc_h = (const float*)d_in[21];
  const float* Wl_h = (const float*)d_in[22];
  const float* bl_h = (const float*)d_in[23];
  const float* att  = (const float*)d_in[24];
  const float* W1   = (const float*)d_in[25];
  const float* b1   = (const float*)d_in[26];
  const float* W2   = (const float*)d_in[27];
  const float* b2   = (const float*)d_in[28];

  float* ws     = (float*)d_ws;
  float* deg    = ws + WS_DEG;
  int*   cnt    = (int*)(ws + WS_CNT);
  float* Mv     = ws + WS_MV;
  int*   tctr   = (int*)(ws + WS_TCTR);
  short* Wp     = (short*)(ws + WS_WP);
  float* W2t    = ws + WS_W2T;
  int2*  bucket = (int2*)(ws + WS_BUCKET);

  float* y_out = (float*)d_out;            // [N,12]
  float* h_out = y_out + N * OUTD;         // [N,256]

  hipMemsetAsync(deg, 0, WS_ZEND * sizeof(float), stream);  // deg+cnt+Mv+tctr

  k_prep<<<200 + EB, 256, 0, stream>>>(Wc_z, bc_z, Wl_z, bl_z,
                                       Wc_h, bc_h, Wl_h, bl_h,
                                       att, W1, W2,
                                       eIA, eKS, eKY, eOH, eWI,
                                       aIA, aKS, aKY, aOH, aWI,
                                       Mv, Wp, W2t, deg, cnt, bucket);
  k_fused<<<FGRID, 256, 0, stream>>>(x, deg, cnt, bucket, Mv, Wp, b1, W2t, b2,
                                     tctr, y_out, h_out);
}

// Round 5
// 180.588 us; speedup vs baseline: 1.7595x; 1.2525x over previous
//
#include <hip/hip_runtime.h>

// ---- problem constants ----
constexpr int N    = 20000;
constexpr int T    = 12;
constexpr int C    = 256;
constexpr int HIDN = 128;
constexpr int OUTD = 12;
constexpr int ER   = 30000;
constexpr int NFT  = 48;               // F*T floats per node
constexpr int EDGE_TOT = 5 * ER;       // 150000
constexpr int CAP      = 32;           // combined bucket capacity (mean 7.5 edges/node)
constexpr int EB       = 586;          // edge blocks = ceil(150000/256)
constexpr int NT       = N / 16;       // 1250 node tiles (all co-resident: 8/CU LDS cap)

// workspace layout (4-byte units); deg+cnt+Mv contiguous -> ONE memset
constexpr int WS_DEG    = 0;          // [100000] float
constexpr int WS_CNT    = 100000;     // [20000] int
constexpr int WS_MV     = 120000;     // [10*C + T] float (atomically accumulated)
constexpr int WS_ZEND   = 122576;     // memset end (floats)
constexpr int WS_WP     = 122576;     // 32768 bf16 = 16384 floats (W1 B-frags)
constexpr int WS_W2T    = 138960;     // [OUTD*HIDN] float
constexpr int WS_BUCKET = 140496;     // [N*CAP] int2 (src|r<<15, w-bits), 8B-aligned

constexpr float LOG2E = 1.4426950408889634f;

typedef __attribute__((ext_vector_type(8))) short short8;
typedef __attribute__((ext_vector_type(4))) float floatx4;
typedef __attribute__((ext_vector_type(2))) float floatx2;

#if __has_builtin(__builtin_amdgcn_exp2f)
#define EXP2(x) __builtin_amdgcn_exp2f(x)
#else
#define EXP2(x) exp2f(x)
#endif

__device__ __forceinline__ floatx2 pk_fma(floatx2 a, floatx2 b, floatx2 c) {
  floatx2 r;
  r.x = fmaf(a.x, b.x, c.x);
  r.y = fmaf(a.y, b.y, c.y);
  return r;                            // -> v_pk_fma_f32
}

__device__ __forceinline__ short f2bf(float f) {   // RNE float->bf16
  unsigned u = __float_as_uint(f);
  u = u + 0x7fffu + ((u >> 16) & 1u);
  return (short)(u >> 16);
}

__device__ __forceinline__ void pick_region(
    int r,
    const int* e0, const int* e1, const int* e2, const int* e3, const int* e4,
    const float* a0, const float* a1, const float* a2, const float* a3, const float* a4,
    const int*& ei, const float*& ea) {
  switch (r) {
    case 0: ei = e0; ea = a0; break;
    case 1: ei = e1; ea = a1; break;
    case 2: ei = e2; ea = a2; break;
    case 3: ei = e3; ea = a3; break;
    default: ei = e4; ea = a4; break;
  }
}

// 1) single prep pass (order-independent; coef math deferred to k_fused):
//    b<64      : weight-collapse PARTIALS, 8 c's per block with UNROLLED loop
//                (parallelized: kills the old 32-iter serial load-latency chain)
//                -> atomicAdd Mv (z pre-scaled log2e, h 2*log2e)
//    b==64     : softmax(att)
//    65<=b<200 : W1 -> bf16 MFMA-B frags; W2 -> W2t
//    b>=200    : deg[r*N+dst] += w  AND  bucket[dst] push (src|r<<15, raw w)
__global__ void k_prep(
    const float* __restrict__ Wc_z, const float* __restrict__ bc_z,
    const float* __restrict__ Wl_z, const float* __restrict__ bl_z,
    const float* __restrict__ Wc_h, const float* __restrict__ bc_h,
    const float* __restrict__ Wl_h, const float* __restrict__ bl_h,
    const float* __restrict__ att, const float* __restrict__ W1,
    const float* __restrict__ W2,
    const int* __restrict__ e0, const int* __restrict__ e1,
    const int* __restrict__ e2, const int* __restrict__ e3,
    const int* __restrict__ e4,
    const float* __restrict__ a0, const float* __restrict__ a1,
    const float* __restrict__ a2, const float* __restrict__ a3,
    const float* __restrict__ a4,
    float* __restrict__ Mv, short* __restrict__ Wp, float* __restrict__ W2t,
    float* __restrict__ deg, int* __restrict__ cnt, int2* __restrict__ bucket) {
  int b = blockIdx.x, tid = threadIdx.x;
  if (b < 64) {
    int g  = b >> 5;                  // 0: z-gate, 1: h-gate
    int ch = b & 31;                  // 32 chunks of 8 c's
    int k  = tid;
    const float* Wc = g ? Wc_h : Wc_z;
    const float* bc = g ? bc_h : bc_z;
    const float* Wl = g ? Wl_h : Wl_z;
    const float* bl = g ? bl_h : bl_z;
    float scale = g ? 2.0f * LOG2E : LOG2E;
    float m0 = 0.f, m1 = 0.f, m2 = 0.f, m3 = 0.f;
    float v = (ch == 0) ? bl[k] : 0.0f;
    int c0 = ch * 8;
#pragma unroll
    for (int cc = 0; cc < 8; cc++) {
      int c = c0 + cc;
      float wl = Wl[c * C + k];
      m0 = fmaf(Wc[0 * C + c], wl, m0);
      m1 = fmaf(Wc[1 * C + c], wl, m1);
      m2 = fmaf(Wc[2 * C + c], wl, m2);
      m3 = fmaf(Wc[3 * C + c], wl, m3);
      v  = fmaf(bc[c], wl, v);
    }
    float* o = Mv + g * (5 * C);
    atomicAdd(&o[0 * C + k], scale * m0);
    atomicAdd(&o[1 * C + k], scale * m1);
    atomicAdd(&o[2 * C + k], scale * m2);
    atomicAdd(&o[3 * C + k], scale * m3);
    atomicAdd(&o[4 * C + k], scale * v);
    return;
  }
  if (b == 64) {
    if (tid < T) {
      float amax = -3.0e38f;
      for (int t = 0; t < T; t++) amax = fmaxf(amax, att[t]);
      float s = 0.f;
      for (int t = 0; t < T; t++) s += __expf(att[t] - amax);
      Mv[10 * C + tid] = __expf(att[tid] - amax) / s;
    }
    return;
  }
  if (b < 200) {
    int idx = (b - 65) * 256 + tid;
    if (idx < 32768) {
      int j    = idx & 7;
      int lane = (idx >> 3) & 63;
      int ch   = (idx >> 9) & 7;
      int kt   = idx >> 12;
      int cin  = ch * 32 + (lane >> 4) * 8 + j;   // K index
      int kout = kt * 16 + (lane & 15);           // N index
      Wp[idx] = f2bf(W1[cin * HIDN + kout]);
    } else if (idx < 32768 + 1536) {
      int r = idx - 32768;
      int o = r >> 7, k = r & 127;
      W2t[r] = W2[k * OUTD + o];
    }
    return;
  }
  int i = (b - 200) * 256 + tid;
  if (i >= EDGE_TOT) return;
  int r = i / ER;
  int e = i - r * ER;
  const int* ei; const float* ea;
  pick_region(r, e0, e1, e2, e3, e4, a0, a1, a2, a3, a4, ei, ea);
  int src = ei[e];
  int dst = ei[ER + e];
  float w = ea[e];
  atomicAdd(&deg[r * N + dst], w);
  int slot = atomicAdd(&cnt[dst], 1);
  if (slot < CAP) bucket[dst * CAP + slot] = make_int2(src | (r << 15), __float_as_int(w));
}

// 2) fused gather + gates + attention pooling + MLP.  Block = 16 nodes, 4
//    waves, static grid of 1250 blocks (all co-resident: LDS 19968B -> 8
//    blocks/CU cap, 1250 < 2048).  ROUND-1 BODY (VGPR 48 — verified 51.5us;
//    round-4's unified gather + pr-hoist hit the 64-VGPR occupancy cliff).
//    Gather: wave w loads nodes w*4..+4 into LDS xs (lane = feature q);
//    bucket slots in lanes 0..31, per-slot coef computed wave-parallel
//    (deferred-coef), (src,cf) broadcast via __shfl, 4-wide unrolled
//    accumulate with masked slots.  Gates: wave owns half (w&1) of all 16
//    nodes, lane owns 2 channels.  fp32 h -> global, bf16 relu(h) -> LDS.
//    16 MFMAs/wave layer-1 + tiny layer-2.
__global__ __launch_bounds__(256) void k_fused(
    const float* __restrict__ x, const float* __restrict__ deg,
    const int* __restrict__ cnt, const int2* __restrict__ bucket,
    const float* __restrict__ Mv, const short* __restrict__ Wp,
    const float* __restrict__ b1, const float* __restrict__ W2t,
    const float* __restrict__ b2,
    float* __restrict__ y_out, float* __restrict__ h_out) {
  __shared__ float xs[16][NFT];       // gathered features (rows 192B, 16B-aligned)
  __shared__ short hs[16][264];       // bf16 relu(h), pad 256->264
  __shared__ float y1s[16][132];      // fp32 layer-1 out, pad 128->132
  int tid = threadIdx.x;
  int wave = tid >> 6, lane = tid & 63;
  int n0 = blockIdx.x * 16;

  // ---- gather phase: 4 nodes per wave, lane = feature q ----
  {
    int q = lane < NFT ? lane : NFT - 1;
    int sl = lane & (CAP - 1);
    int nb = n0 + wave * 4;
    int4 cv4 = *(const int4*)&cnt[nb];
    int cvs[4] = {cv4.x, cv4.y, cv4.z, cv4.w};
    int2 mrs[4];
#pragma unroll
    for (int nl = 0; nl < 4; nl++) mrs[nl] = bucket[(nb + nl) * CAP + sl];

#pragma unroll
    for (int nl = 0; nl < 4; nl++) {
      int rl = wave * 4 + nl;
      int n = nb + nl;
      // per-region dinv of this (dst) node — broadcast loads
      float dd0 = rsqrtf(deg[0 * N + n] + 1.0f);
      float dd1 = rsqrtf(deg[1 * N + n] + 1.0f);
      float dd2 = rsqrtf(deg[2 * N + n] + 1.0f);
      float dd3 = rsqrtf(deg[3 * N + n] + 1.0f);
      float dd4 = rsqrtf(deg[4 * N + n] + 1.0f);
      float s = dd0 * dd0 + dd1 * dd1 + dd2 * dd2 + dd3 * dd3 + dd4 * dd4;
      float facc = s * x[n * NFT + q];

      int cv = cvs[nl];
      if (cv > CAP) cv = CAP;
      // wave-parallel per-slot coefficient (lanes 0..31 own the slots)
      int2 m  = mrs[nl];
      bool valid = sl < cv;
      int key  = valid ? m.x : 0;        // masked slots -> node 0, cf 0
      int srcv = key & 0x7fff;
      int rr   = key >> 15;
      float dsrc = deg[rr * N + srcv];   // one 32-lane random load (L2-resident)
      float ddn = rr == 0 ? dd0 : rr == 1 ? dd1 : rr == 2 ? dd2
                : rr == 3 ? dd3 : dd4;
      float cf = valid ? rsqrtf(dsrc + 1.0f) * __int_as_float(m.y) * ddn : 0.0f;

      // 4-wide accumulate, no tail (cv rounded up; masked slots are no-ops)
      float f1 = 0.f, f2 = 0.f, f3 = 0.f;
      int cvr = (cv + 3) & ~3;
      for (int j = 0; j < cvr; j += 4) {
        int s0 = __shfl(srcv, j);
        int s1 = __shfl(srcv, j + 1);
        int s2 = __shfl(srcv, j + 2);
        int s3 = __shfl(srcv, j + 3);
        float c0 = __shfl(cf, j);
        float c1 = __shfl(cf, j + 1);
        float c2 = __shfl(cf, j + 2);
        float c3 = __shfl(cf, j + 3);
        float x0 = x[s0 * NFT + q];
        float x1 = x[s1 * NFT + q];
        float x2 = x[s2 * NFT + q];
        float x3 = x[s3 * NFT + q];
        facc = fmaf(c0, x0, facc);
        f1 = fmaf(c1, x1, f1);
        f2 = fmaf(c2, x2, f2);
        f3 = fmaf(c3, x3, f3);
      }
      facc = (facc + f1) + (f2 + f3);
      if (lane < NFT) xs[rl][lane] = facc;
    }
  }
  __syncthreads();

  // ---- gates phase: half = wave&1, nodes (wave>>1)*8..+8, 2 ch/lane ----
  {
    int half = wave & 1;
    int nb   = (wave >> 1) * 8;
    int c0 = half * 128 + (lane << 1);
    const float* Mz = Mv;               // pre-scaled by log2e
    const float* Mh = Mv + 5 * C;       // pre-scaled by 2*log2e
    floatx2 mz[4], mh[4], vz, vh;
#pragma unroll
    for (int f = 0; f < 4; f++) {
      mz[f] = *(const floatx2*)(Mz + f * C + c0);
      mh[f] = *(const floatx2*)(Mh + f * C + c0);
    }
    vz = *(const floatx2*)(Mz + 4 * C + c0);
    vh = *(const floatx2*)(Mh + 4 * C + c0);

#pragma unroll
    for (int nl = 0; nl < 8; nl++) {
      int rl = nb + nl;                  // local node 0..15
      int n = n0 + rl;
      const float* xr = &xs[rl][0];      // LDS, broadcast reads
      floatx2 acc = {0.f, 0.f};
#pragma unroll
      for (int tb = 0; tb < 3; tb++) {
        float4 xf0 = *(const float4*)(xr + 0 * T + tb * 4);
        float4 xf1 = *(const float4*)(xr + 1 * T + tb * 4);
        float4 xf2 = *(const float4*)(xr + 2 * T + tb * 4);
        float4 xf3 = *(const float4*)(xr + 3 * T + tb * 4);
        float xs0[4] = {xf0.x, xf0.y, xf0.z, xf0.w};
        float xs1[4] = {xf1.x, xf1.y, xf1.z, xf1.w};
        float xs2[4] = {xf2.x, xf2.y, xf2.z, xf2.w};
        float xs3[4] = {xf3.x, xf3.y, xf3.z, xf3.w};
#pragma unroll
        for (int tt = 0; tt < 4; tt++) {
          int t = tb * 4 + tt;
          float p = Mv[10 * C + t];      // uniform address -> s_load
          floatx2 x0 = {xs0[tt], xs0[tt]};
          floatx2 x1 = {xs1[tt], xs1[tt]};
          floatx2 x2 = {xs2[tt], xs2[tt]};
          floatx2 x3 = {xs3[tt], xs3[tt]};
          floatx2 az = pk_fma(mz[0], x0, pk_fma(mz[1], x1, pk_fma(mz[2], x2, pk_fma(mz[3], x3, vz))));
          floatx2 ah = pk_fma(mh[0], x0, pk_fma(mh[1], x1, pk_fma(mh[2], x2, pk_fma(mh[3], x3, vh))));
          floatx2 e1, e2;
          e1.x = EXP2(az.x); e1.y = EXP2(az.y);        // e^{az_true}
          e2.x = EXP2(ah.x); e2.y = EXP2(ah.y);        // e^{2*ah_true}
          floatx2 one = {1.f, 1.f};
          floatx2 d1 = e1 + one;
          floatx2 d2 = e2 + one;
          floatx2 rD;
          rD.x = __builtin_amdgcn_rcpf(d1.x * d2.x);
          rD.y = __builtin_amdgcn_rcpf(d1.y * d2.y);
          floatx2 pv = {p, p};
          floatx2 pn = pk_fma(pv, e2, -pv);            // p*(e2-1)
          acc = pk_fma(pn, rD, acc);
        }
      }
      float2 o = {acc.x, acc.y};
      *(float2*)(h_out + n * C + c0) = o;               // required fp32 output
      unsigned pk = (unsigned short)f2bf(fmaxf(acc.x, 0.f)) |
                    ((unsigned)(unsigned short)f2bf(fmaxf(acc.y, 0.f)) << 16);
      *(unsigned*)&hs[rl][c0] = pk;                     // bf16 relu(h) -> LDS
    }
  }
  __syncthreads();

  // ---- layer 1: 16 MFMAs per wave (kt = wave*2, wave*2+1) ----
  {
    int quad = lane >> 4, col = lane & 15;
    floatx4 acc2[2];
    acc2[0] = {0.f, 0.f, 0.f, 0.f};
    acc2[1] = {0.f, 0.f, 0.f, 0.f};
#pragma unroll
    for (int ch = 0; ch < 8; ch++) {
      short8 a = *(const short8*)&hs[col][ch * 32 + quad * 8];
#pragma unroll
      for (int kk = 0; kk < 2; kk++) {
        short8 bb = ((const short8*)Wp)[((wave * 2 + kk) * 8 + ch) * 64 + lane];
        acc2[kk] = __builtin_amdgcn_mfma_f32_16x16x32_bf16(a, bb, acc2[kk], 0, 0, 0);
      }
    }
#pragma unroll
    for (int kk = 0; kk < 2; kk++) {
      int kt = wave * 2 + kk;
      float bias = b1[kt * 16 + col];
#pragma unroll
      for (int r = 0; r < 4; r++)
        y1s[quad * 4 + r][kt * 16 + col] = fmaxf(acc2[kk][r] + bias, 0.f);
    }
  }
  __syncthreads();

  // ---- layer 2: 16 nodes x 12 outputs = 192 threads ----
  if (tid < 16 * OUTD) {
    int nl = tid / OUTD, o = tid - nl * OUTD;
    float sacc = b2[o];
    const float* yr = &y1s[nl][0];
    const float* wr = W2t + o * HIDN;
#pragma unroll 8
    for (int k4 = 0; k4 < 32; k4++) {
      float4 yv = *(const float4*)(yr + 4 * k4);
      float4 wv = *(const float4*)(wr + 4 * k4);
      sacc = fmaf(yv.x, wv.x, fmaf(yv.y, wv.y, fmaf(yv.z, wv.z, fmaf(yv.w, wv.w, sacc))));
    }
    y_out[(n0 + nl) * OUTD + o] = sacc;
  }
}

extern "C" void kernel_launch(void* const* d_in, const int* in_sizes, int n_in,
                              void* d_out, int out_size, void* d_ws, size_t ws_size,
                              hipStream_t stream) {
  const float* x   = (const float*)d_in[0];
  // d_in[1] full-graph edge_index: provably unused
  const int* eIA = (const int*)d_in[2];
  const int* eKS = (const int*)d_in[3];
  const int* eKY = (const int*)d_in[4];
  const int* eOH = (const int*)d_in[5];
  const int* eWI = (const int*)d_in[6];
  const float* aIA = (const float*)d_in[7];
  const float* aKS = (const float*)d_in[8];
  const float* aKY = (const float*)d_in[9];
  const float* aOH = (const float*)d_in[10];
  const float* aWI = (const float*)d_in[11];
  const float* Wc_z = (const float*)d_in[12];
  const float* bc_z = (const float*)d_in[13];
  const float* Wl_z = (const float*)d_in[14];
  const float* bl_z = (const float*)d_in[15];
  // r-gate params (16..19) cannot influence the output (H=0)
  const float* Wc_h = (const float*)d_in[20];
  const float* bc_h = (const float*)d_in[21];
  const float* Wl_h = (const float*)d_in[22];
  const float* bl_h = (const float*)d_in[23];
  const float* att  = (const float*)d_in[24];
  const float* W1   = (const float*)d_in[25];
  const float* b1   = (const float*)d_in[26];
  const float* W2   = (const float*)d_in[27];
  const float* b2   = (const float*)d_in[28];

  float* ws     = (float*)d_ws;
  float* deg    = ws + WS_DEG;
  int*   cnt    = (int*)(ws + WS_CNT);
  float* Mv     = ws + WS_MV;
  short* Wp     = (short*)(ws + WS_WP);
  float* W2t    = ws + WS_W2T;
  int2*  bucket = (int2*)(ws + WS_BUCKET);

  float* y_out = (float*)d_out;            // [N,12]
  float* h_out = y_out + N * OUTD;         // [N,256]

  hipMemsetAsync(deg, 0, WS_ZEND * sizeof(float), stream);  // deg + cnt + Mv

  k_prep<<<200 + EB, 256, 0, stream>>>(Wc_z, bc_z, Wl_z, bl_z,
                                       Wc_h, bc_h, Wl_h, bl_h,
                                       att, W1, W2,
                                       eIA, eKS, eKY, eOH, eWI,
                                       aIA, aKS, aKY, aOH, aWI,
                                       Mv, Wp, W2t, deg, cnt, bucket);
  k_fused<<<NT, 256, 0, stream>>>(x, deg, cnt, bucket, Mv, Wp, b1, W2t, b2,
                                  y_out, h_out);
}

// Round 6
// 176.855 us; speedup vs baseline: 1.7967x; 1.0211x over previous
//
#include <hip/hip_runtime.h>

// ---- problem constants ----
constexpr int N    = 20000;
constexpr int T    = 12;
constexpr int C    = 256;
constexpr int HIDN = 128;
constexpr int OUTD = 12;
constexpr int ER   = 30000;
constexpr int NFT  = 48;               // F*T floats per node
constexpr int EDGE_TOT = 5 * ER;       // 150000
constexpr int CAP      = 32;           // combined bucket capacity (mean 7.5 edges/node)
constexpr int EB       = 586;          // edge blocks = ceil(150000/256)
constexpr int NT       = N / 16;       // 1250 node tiles (all co-resident: 8/CU LDS cap)

// workspace layout (4-byte units); deg+cnt+Mv contiguous -> ONE memset
constexpr int WS_DEG    = 0;          // [100000] float
constexpr int WS_CNT    = 100000;     // [20000] int
constexpr int WS_MV     = 120000;     // [10*C + T] float (atomically accumulated)
constexpr int WS_ZEND   = 122576;     // memset end (floats)
constexpr int WS_WP     = 122576;     // 32768 bf16 = 16384 floats (W1 B-frags)
constexpr int WS_W2T    = 138960;     // [OUTD*HIDN] float
constexpr int WS_BUCKET = 140496;     // [N*CAP] int2 (src|r<<15, w-bits), 8B-aligned

constexpr float LOG2E = 1.4426950408889634f;

typedef __attribute__((ext_vector_type(8))) short short8;
typedef __attribute__((ext_vector_type(4))) float floatx4;
typedef __attribute__((ext_vector_type(2))) float floatx2;

#if __has_builtin(__builtin_amdgcn_exp2f)
#define EXP2(x) __builtin_amdgcn_exp2f(x)
#else
#define EXP2(x) exp2f(x)
#endif

__device__ __forceinline__ floatx2 pk_fma(floatx2 a, floatx2 b, floatx2 c) {
  floatx2 r;
  r.x = fmaf(a.x, b.x, c.x);
  r.y = fmaf(a.y, b.y, c.y);
  return r;                            // -> v_pk_fma_f32
}

__device__ __forceinline__ short f2bf(float f) {   // RNE float->bf16
  unsigned u = __float_as_uint(f);
  u = u + 0x7fffu + ((u >> 16) & 1u);
  return (short)(u >> 16);
}

__device__ __forceinline__ void pick_region(
    int r,
    const int* e0, const int* e1, const int* e2, const int* e3, const int* e4,
    const float* a0, const float* a1, const float* a2, const float* a3, const float* a4,
    const int*& ei, const float*& ea) {
  switch (r) {
    case 0: ei = e0; ea = a0; break;
    case 1: ei = e1; ea = a1; break;
    case 2: ei = e2; ea = a2; break;
    case 3: ei = e3; ea = a3; break;
    default: ei = e4; ea = a4; break;
  }
}

// 1) single prep pass (order-independent; coef math deferred to k_fused):
//    b<64      : weight-collapse PARTIALS, 8 c's per block, unrolled
//    b==64     : softmax(att)
//    65<=b<200 : W1 -> bf16 MFMA-B frags; W2 -> W2t
//    b>=200    : deg[r*N+dst] += w  AND  bucket[dst] push (src|r<<15, raw w)
__global__ void k_prep(
    const float* __restrict__ Wc_z, const float* __restrict__ bc_z,
    const float* __restrict__ Wl_z, const float* __restrict__ bl_z,
    const float* __restrict__ Wc_h, const float* __restrict__ bc_h,
    const float* __restrict__ Wl_h, const float* __restrict__ bl_h,
    const float* __restrict__ att, const float* __restrict__ W1,
    const float* __restrict__ W2,
    const int* __restrict__ e0, const int* __restrict__ e1,
    const int* __restrict__ e2, const int* __restrict__ e3,
    const int* __restrict__ e4,
    const float* __restrict__ a0, const float* __restrict__ a1,
    const float* __restrict__ a2, const float* __restrict__ a3,
    const float* __restrict__ a4,
    float* __restrict__ Mv, short* __restrict__ Wp, float* __restrict__ W2t,
    float* __restrict__ deg, int* __restrict__ cnt, int2* __restrict__ bucket) {
  int b = blockIdx.x, tid = threadIdx.x;
  if (b < 64) {
    int g  = b >> 5;                  // 0: z-gate, 1: h-gate
    int ch = b & 31;                  // 32 chunks of 8 c's
    int k  = tid;
    const float* Wc = g ? Wc_h : Wc_z;
    const float* bc = g ? bc_h : bc_z;
    const float* Wl = g ? Wl_h : Wl_z;
    const float* bl = g ? bl_h : bl_z;
    float scale = g ? 2.0f * LOG2E : LOG2E;
    float m0 = 0.f, m1 = 0.f, m2 = 0.f, m3 = 0.f;
    float v = (ch == 0) ? bl[k] : 0.0f;
    int c0 = ch * 8;
#pragma unroll
    for (int cc = 0; cc < 8; cc++) {
      int c = c0 + cc;
      float wl = Wl[c * C + k];
      m0 = fmaf(Wc[0 * C + c], wl, m0);
      m1 = fmaf(Wc[1 * C + c], wl, m1);
      m2 = fmaf(Wc[2 * C + c], wl, m2);
      m3 = fmaf(Wc[3 * C + c], wl, m3);
      v  = fmaf(bc[c], wl, v);
    }
    float* o = Mv + g * (5 * C);
    atomicAdd(&o[0 * C + k], scale * m0);
    atomicAdd(&o[1 * C + k], scale * m1);
    atomicAdd(&o[2 * C + k], scale * m2);
    atomicAdd(&o[3 * C + k], scale * m3);
    atomicAdd(&o[4 * C + k], scale * v);
    return;
  }
  if (b == 64) {
    if (tid < T) {
      float amax = -3.0e38f;
      for (int t = 0; t < T; t++) amax = fmaxf(amax, att[t]);
      float s = 0.f;
      for (int t = 0; t < T; t++) s += __expf(att[t] - amax);
      Mv[10 * C + tid] = __expf(att[tid] - amax) / s;
    }
    return;
  }
  if (b < 200) {
    int idx = (b - 65) * 256 + tid;
    if (idx < 32768) {
      int j    = idx & 7;
      int lane = (idx >> 3) & 63;
      int ch   = (idx >> 9) & 7;
      int kt   = idx >> 12;
      int cin  = ch * 32 + (lane >> 4) * 8 + j;   // K index
      int kout = kt * 16 + (lane & 15);           // N index
      Wp[idx] = f2bf(W1[cin * HIDN + kout]);
    } else if (idx < 32768 + 1536) {
      int r = idx - 32768;
      int o = r >> 7, k = r & 127;
      W2t[r] = W2[k * OUTD + o];
    }
    return;
  }
  int i = (b - 200) * 256 + tid;
  if (i >= EDGE_TOT) return;
  int r = i / ER;
  int e = i - r * ER;
  const int* ei; const float* ea;
  pick_region(r, e0, e1, e2, e3, e4, a0, a1, a2, a3, a4, ei, ea);
  int src = ei[e];
  int dst = ei[ER + e];
  float w = ea[e];
  atomicAdd(&deg[r * N + dst], w);
  int slot = atomicAdd(&cnt[dst], 1);
  if (slot < CAP) bucket[dst * CAP + slot] = make_int2(src | (r << 15), __float_as_int(w));
}

// 2) fused gather + gates + attention pooling + MLP.  Block = 16 nodes, 4
//    waves, static grid of 1250 blocks.  VGPR-48 structure (round-1/5
//    verified 51.5us) with TWO targeted changes:
//    (a) gather broadcasts (src,cf) via LDS instead of __shfl: lanes 0..31
//        compute per-slot coef and ds_write one int2; the edge loop then
//        reads 4 pairs per step with TWO uniform-address ds_read_b128
//        (broadcast, conflict-free) -> ~5 DS ops/node instead of ~20
//        ds_bpermute, and the x-row loads issue without a bpermute chain
//        in front.  Staging buffer OVERLAYS y1s (only live after the
//        gather barrier) so LDS stays exactly 19968B.
//    (b) layer-2 dot product split into 4 independent fma chains
//        (was one 128-deep serial chain in the block tail).
__global__ __launch_bounds__(256) void k_fused(
    const float* __restrict__ x, const float* __restrict__ deg,
    const int* __restrict__ cnt, const int2* __restrict__ bucket,
    const float* __restrict__ Mv, const short* __restrict__ Wp,
    const float* __restrict__ b1, const float* __restrict__ W2t,
    const float* __restrict__ b2,
    float* __restrict__ y_out, float* __restrict__ h_out) {
  __shared__ float xs[16][NFT];       // gathered features (rows 192B, 16B-aligned)
  __shared__ short hs[16][264];       // bf16 relu(h), pad 256->264
  __shared__ union {
    int2  prs[4][4][32];              // gather-phase (src,cf) staging (4KB)
    float y1s[16][132];               // fp32 layer-1 out (post-barrier phases)
  } u;                                // overlay keeps LDS at 19968B
  int tid = threadIdx.x;
  int wave = tid >> 6, lane = tid & 63;
  int n0 = blockIdx.x * 16;

  // ---- gather phase: 4 nodes per wave, lane = feature q ----
  {
    int q = lane < NFT ? lane : NFT - 1;
    int sl = lane & (CAP - 1);
    int nb = n0 + wave * 4;
    int4 cv4 = *(const int4*)&cnt[nb];
    int cvs[4] = {cv4.x, cv4.y, cv4.z, cv4.w};
    int2 mrs[4];
#pragma unroll
    for (int nl = 0; nl < 4; nl++) mrs[nl] = bucket[(nb + nl) * CAP + sl];

    // pass 1: per-node dst dinv, self term, per-slot coef -> LDS
    float selfv[4];
#pragma unroll
    for (int nl = 0; nl < 4; nl++) {
      int n = nb + nl;
      float dd0 = rsqrtf(deg[0 * N + n] + 1.0f);
      float dd1 = rsqrtf(deg[1 * N + n] + 1.0f);
      float dd2 = rsqrtf(deg[2 * N + n] + 1.0f);
      float dd3 = rsqrtf(deg[3 * N + n] + 1.0f);
      float dd4 = rsqrtf(deg[4 * N + n] + 1.0f);
      float s = dd0 * dd0 + dd1 * dd1 + dd2 * dd2 + dd3 * dd3 + dd4 * dd4;
      selfv[nl] = s * x[n * NFT + q];

      bool valid = sl < cvs[nl];
      int key  = valid ? mrs[nl].x : 0;        // masked slots -> node 0, cf 0
      int srcv = key & 0x7fff;
      int rr   = key >> 15;
      float dsrc = deg[rr * N + srcv];         // 32-lane random load (L2-resident)
      float ddn = rr == 0 ? dd0 : rr == 1 ? dd1 : rr == 2 ? dd2
                : rr == 3 ? dd3 : dd4;
      float cf = valid ? rsqrtf(dsrc + 1.0f) * __int_as_float(mrs[nl].y) * ddn : 0.0f;
      if (lane < CAP)
        u.prs[wave][nl][sl] = make_int2(srcv, __float_as_int(cf));
    }
    // (compiler inserts the lgkmcnt wait: same-wave ds_write -> ds_read dep)

    // pass 2: edge accumulate, 4-wide, pairs broadcast via uniform ds_read
#pragma unroll 1
    for (int nl = 0; nl < 4; nl++) {
      float facc = selfv[nl], f1 = 0.f, f2 = 0.f, f3 = 0.f;
      int cv = cvs[nl];
      if (cv > CAP) cv = CAP;
      int cvr = (cv + 3) & ~3;
      const int2* pp = &u.prs[wave][nl][0];
      for (int j = 0; j < cvr; j += 4) {
        int4 pa = *(const int4*)(pp + j);       // edges j, j+1  (broadcast)
        int4 pb = *(const int4*)(pp + j + 2);   // edges j+2, j+3
        float x0 = x[pa.x * NFT + q];
        float x1 = x[pa.z * NFT + q];
        float x2 = x[pb.x * NFT + q];
        float x3 = x[pb.z * NFT + q];
        facc = fmaf(__int_as_float(pa.y), x0, facc);
        f1 = fmaf(__int_as_float(pa.w), x1, f1);
        f2 = fmaf(__int_as_float(pb.y), x2, f2);
        f3 = fmaf(__int_as_float(pb.w), x3, f3);
      }
      facc = (facc + f1) + (f2 + f3);
      if (lane < NFT) xs[wave * 4 + nl][lane] = facc;
    }
  }
  __syncthreads();

  // ---- gates phase: half = wave&1, nodes (wave>>1)*8..+8, 2 ch/lane ----
  {
    int half = wave & 1;
    int nb   = (wave >> 1) * 8;
    int c0 = half * 128 + (lane << 1);
    const float* Mz = Mv;               // pre-scaled by log2e
    const float* Mh = Mv + 5 * C;       // pre-scaled by 2*log2e
    floatx2 mz[4], mh[4], vz, vh;
#pragma unroll
    for (int f = 0; f < 4; f++) {
      mz[f] = *(const floatx2*)(Mz + f * C + c0);
      mh[f] = *(const floatx2*)(Mh + f * C + c0);
    }
    vz = *(const floatx2*)(Mz + 4 * C + c0);
    vh = *(const floatx2*)(Mh + 4 * C + c0);

#pragma unroll
    for (int nl = 0; nl < 8; nl++) {
      int rl = nb + nl;                  // local node 0..15
      int n = n0 + rl;
      const float* xr = &xs[rl][0];      // LDS, broadcast reads
      floatx2 acc = {0.f, 0.f};
#pragma unroll
      for (int tb = 0; tb < 3; tb++) {
        float4 xf0 = *(const float4*)(xr + 0 * T + tb * 4);
        float4 xf1 = *(const float4*)(xr + 1 * T + tb * 4);
        float4 xf2 = *(const float4*)(xr + 2 * T + tb * 4);
        float4 xf3 = *(const float4*)(xr + 3 * T + tb * 4);
        float xs0[4] = {xf0.x, xf0.y, xf0.z, xf0.w};
        float xs1[4] = {xf1.x, xf1.y, xf1.z, xf1.w};
        float xs2[4] = {xf2.x, xf2.y, xf2.z, xf2.w};
        float xs3[4] = {xf3.x, xf3.y, xf3.z, xf3.w};
#pragma unroll
        for (int tt = 0; tt < 4; tt++) {
          int t = tb * 4 + tt;
          float p = Mv[10 * C + t];      // uniform address -> s_load
          floatx2 x0 = {xs0[tt], xs0[tt]};
          floatx2 x1 = {xs1[tt], xs1[tt]};
          floatx2 x2 = {xs2[tt], xs2[tt]};
          floatx2 x3 = {xs3[tt], xs3[tt]};
          floatx2 az = pk_fma(mz[0], x0, pk_fma(mz[1], x1, pk_fma(mz[2], x2, pk_fma(mz[3], x3, vz))));
          floatx2 ah = pk_fma(mh[0], x0, pk_fma(mh[1], x1, pk_fma(mh[2], x2, pk_fma(mh[3], x3, vh))));
          floatx2 e1, e2;
          e1.x = EXP2(az.x); e1.y = EXP2(az.y);        // e^{az_true}
          e2.x = EXP2(ah.x); e2.y = EXP2(ah.y);        // e^{2*ah_true}
          floatx2 one = {1.f, 1.f};
          floatx2 d1 = e1 + one;
          floatx2 d2 = e2 + one;
          floatx2 rD;
          rD.x = __builtin_amdgcn_rcpf(d1.x * d2.x);
          rD.y = __builtin_amdgcn_rcpf(d1.y * d2.y);
          floatx2 pv = {p, p};
          floatx2 pn = pk_fma(pv, e2, -pv);            // p*(e2-1)
          acc = pk_fma(pn, rD, acc);
        }
      }
      float2 o = {acc.x, acc.y};
      *(float2*)(h_out + n * C + c0) = o;               // required fp32 output
      unsigned pk = (unsigned short)f2bf(fmaxf(acc.x, 0.f)) |
                    ((unsigned)(unsigned short)f2bf(fmaxf(acc.y, 0.f)) << 16);
      *(unsigned*)&hs[rl][c0] = pk;                     // bf16 relu(h) -> LDS
    }
  }
  __syncthreads();

  // ---- layer 1: 16 MFMAs per wave (kt = wave*2, wave*2+1) ----
  {
    int quad = lane >> 4, col = lane & 15;
    floatx4 acc2[2];
    acc2[0] = {0.f, 0.f, 0.f, 0.f};
    acc2[1] = {0.f, 0.f, 0.f, 0.f};
#pragma unroll
    for (int ch = 0; ch < 8; ch++) {
      short8 a = *(const short8*)&hs[col][ch * 32 + quad * 8];
#pragma unroll
      for (int kk = 0; kk < 2; kk++) {
        short8 bb = ((const short8*)Wp)[((wave * 2 + kk) * 8 + ch) * 64 + lane];
        acc2[kk] = __builtin_amdgcn_mfma_f32_16x16x32_bf16(a, bb, acc2[kk], 0, 0, 0);
      }
    }
#pragma unroll
    for (int kk = 0; kk < 2; kk++) {
      int kt = wave * 2 + kk;
      float bias = b1[kt * 16 + col];
#pragma unroll
      for (int r = 0; r < 4; r++)
        u.y1s[quad * 4 + r][kt * 16 + col] = fmaxf(acc2[kk][r] + bias, 0.f);
    }
  }
  __syncthreads();

  // ---- layer 2: 16 nodes x 12 outputs = 192 threads, 4 fma chains ----
  if (tid < 16 * OUTD) {
    int nl = tid / OUTD, o = tid - nl * OUTD;
    const float* yr = &u.y1s[nl][0];
    const float* wr = W2t + o * HIDN;
    float sa = b2[o], sb = 0.f, sc = 0.f, sd = 0.f;
#pragma unroll
    for (int k16 = 0; k16 < 128; k16 += 16) {
      float4 y0 = *(const float4*)(yr + k16);
      float4 w0 = *(const float4*)(wr + k16);
      float4 y1 = *(const float4*)(yr + k16 + 4);
      float4 w1 = *(const float4*)(wr + k16 + 4);
      float4 y2 = *(const float4*)(yr + k16 + 8);
      float4 w2 = *(const float4*)(wr + k16 + 8);
      float4 y3 = *(const float4*)(yr + k16 + 12);
      float4 w3 = *(const float4*)(wr + k16 + 12);
      sa = fmaf(y0.x, w0.x, fmaf(y0.y, w0.y, fmaf(y0.z, w0.z, fmaf(y0.w, w0.w, sa))));
      sb = fmaf(y1.x, w1.x, fmaf(y1.y, w1.y, fmaf(y1.z, w1.z, fmaf(y1.w, w1.w, sb))));
      sc = fmaf(y2.x, w2.x, fmaf(y2.y, w2.y, fmaf(y2.z, w2.z, fmaf(y2.w, w2.w, sc))));
      sd = fmaf(y3.x, w3.x, fmaf(y3.y, w3.y, fmaf(y3.z, w3.z, fmaf(y3.w, w3.w, sd))));
    }
    y_out[(n0 + nl) * OUTD + o] = (sa + sb) + (sc + sd);
  }
}

extern "C" void kernel_launch(void* const* d_in, const int* in_sizes, int n_in,
                              void* d_out, int out_size, void* d_ws, size_t ws_size,
                              hipStream_t stream) {
  const float* x   = (const float*)d_in[0];
  // d_in[1] full-graph edge_index: provably unused
  const int* eIA = (const int*)d_in[2];
  const int* eKS = (const int*)d_in[3];
  const int* eKY = (const int*)d_in[4];
  const int* eOH = (const int*)d_in[5];
  const int* eWI = (const int*)d_in[6];
  const float* aIA = (const float*)d_in[7];
  const float* aKS = (const float*)d_in[8];
  const float* aKY = (const float*)d_in[9];
  const float* aOH = (const float*)d_in[10];
  const float* aWI = (const float*)d_in[11];
  const float* Wc_z = (const float*)d_in[12];
  const float* bc_z = (const float*)d_in[13];
  const float* Wl_z = (const float*)d_in[14];
  const float* bl_z = (const float*)d_in[15];
  // r-gate params (16..19) cannot influence the output (H=0)
  const float* Wc_h = (const float*)d_in[20];
  const float* bc_h = (const float*)d_in[21];
  const float* Wl_h = (const float*)d_in[22];
  const float* bl_h = (const float*)d_in[23];
  const float* att  = (const float*)d_in[24];
  const float* W1   = (const float*)d_in[25];
  const float* b1   = (const float*)d_in[26];
  const float* W2   = (const float*)d_in[27];
  const float* b2   = (const float*)d_in[28];

  float* ws     = (float*)d_ws;
  float* deg    = ws + WS_DEG;
  int*   cnt    = (int*)(ws + WS_CNT);
  float* Mv     = ws + WS_MV;
  short* Wp     = (short*)(ws + WS_WP);
  float* W2t    = ws + WS_W2T;
  int2*  bucket = (int2*)(ws + WS_BUCKET);

  float* y_out = (float*)d_out;            // [N,12]
  float* h_out = y_out + N * OUTD;         // [N,256]

  hipMemsetAsync(deg, 0, WS_ZEND * sizeof(float), stream);  // deg + cnt + Mv

  k_prep<<<200 + EB, 256, 0, stream>>>(Wc_z, bc_z, Wl_z, bl_z,
                                       Wc_h, bc_h, Wl_h, bl_h,
                                       att, W1, W2,
                                       eIA, eKS, eKY, eOH, eWI,
                                       aIA, aKS, aKY, aOH, aWI,
                                       Mv, Wp, W2t, deg, cnt, bucket);
  k_fused<<<NT, 256, 0, stream>>>(x, deg, cnt, bucket, Mv, Wp, b1, W2t, b2,
                                  y_out, h_out);
}